// Round 9
// baseline (204.504 us; speedup 1.0000x reference)
//
#include <hip/hip_runtime.h>
#include <hip/hip_bf16.h>
#include <math.h>

// Problem constants
constexpr int Tq  = 4096;   // sequence length
constexpr int D   = 1024;   // model dim
constexpr int H   = 16;     // query heads
constexpr int HKV = 4;      // kv heads
constexpr int HD  = 64;     // head dim
constexpr int NQKV = D + 2 * HKV * HD;   // 1536

typedef __attribute__((ext_vector_type(8))) short bf16x8;
typedef __attribute__((ext_vector_type(4))) float f32x4;

static __device__ inline unsigned short f2bf(float f) {
    __hip_bfloat16 h = __float2bfloat16(f);
    return *reinterpret_cast<unsigned short*>(&h);
}
static __device__ inline unsigned short rnbf(float f) {   // RN for positive finite
    unsigned int u = __float_as_uint(f);
    return (unsigned short)((u + 0x8000u) >> 16);
}
static __device__ inline float bf2f(unsigned short u) {
    unsigned int x = ((unsigned int)u) << 16;
    return __uint_as_float(x);
}

#define GLOBAL_LOAD_LDS16(g, l)                                                   \
    __builtin_amdgcn_global_load_lds(                                             \
        (const __attribute__((address_space(1))) void*)(g),                       \
        (__attribute__((address_space(3))) void*)(l), 16, 0, 0)

// ---------------------------------------------------------------------------
// fused f32 -> bf16 convert for x, w_qkv, w_proj (one launch)
// ---------------------------------------------------------------------------
__global__ __launch_bounds__(256)
void to_bf16_all(const float* __restrict__ x, const float* __restrict__ wq,
                 const float* __restrict__ wp,
                 unsigned short* __restrict__ xb, unsigned short* __restrict__ wqb,
                 unsigned short* __restrict__ wpb)
{
    const int N1 = Tq * D, N2 = NQKV * D;
    int i = (blockIdx.x * 256 + threadIdx.x) * 4;
    const float* s; unsigned short* d;
    if (i < N1)            { s = x + i;             d = xb + i; }
    else if (i < N1 + N2)  { s = wq + (i - N1);     d = wqb + (i - N1); }
    else                   { s = wp + (i - N1 - N2); d = wpb + (i - N1 - N2); }
    float4 v = *(const float4*)s;
    ushort4 o;
    o.x = f2bf(v.x); o.y = f2bf(v.y); o.z = f2bf(v.z); o.w = f2bf(v.w);
    *(ushort4*)d = o;
}

// ---------------------------------------------------------------------------
// bf16 MFMA GEMM mainloop (m97 structure): C[M,N] = A[M,K] @ B[N,K]^T
// 128x128 tile, BK=32, 4 waves each 64x64.  (verified rounds 3/5/6/7/8)
// ---------------------------------------------------------------------------
#define GEMM_MAINLOOP(Aptr, Bptr, Kdim)                                           \
    __shared__ __align__(16) unsigned short As[128 * 32];                         \
    __shared__ __align__(16) unsigned short Bs[128 * 32];                         \
    const int tid  = threadIdx.x;                                                 \
    const int lane = tid & 63;                                                    \
    const int w    = tid >> 6;                                                    \
    const int l15  = lane & 15, quad = lane >> 4;                                 \
    const int wm   = w >> 1, wn = w & 1;                                          \
    const int m0   = blockIdx.x * 128, n0 = blockIdx.y * 128;                     \
    const int srow   = lane >> 2;                                                 \
    const int schunk = (lane & 3) ^ ((lane >> 3) & 3);                            \
    const int fs     = (quad ^ ((l15 >> 1) & 3)) * 8;                             \
    f32x4 acc[4][4];                                                              \
    _Pragma("unroll")                                                             \
    for (int i = 0; i < 4; ++i)                                                   \
        _Pragma("unroll")                                                         \
        for (int j = 0; j < 4; ++j) acc[i][j] = (f32x4){0.f, 0.f, 0.f, 0.f};      \
    for (int k0 = 0; k0 < (Kdim); k0 += 32) {                                     \
        __syncthreads();                                                          \
        _Pragma("unroll")                                                         \
        for (int it = 0; it < 2; ++it) {                                          \
            const int r = w * 32 + it * 16 + srow;                                \
            GLOBAL_LOAD_LDS16((Aptr) + (size_t)(m0 + r) * (Kdim) + k0 + schunk * 8,\
                              &As[(w * 32 + it * 16) * 32]);                      \
            GLOBAL_LOAD_LDS16((Bptr) + (size_t)(n0 + r) * (Kdim) + k0 + schunk * 8,\
                              &Bs[(w * 32 + it * 16) * 32]);                      \
        }                                                                         \
        __syncthreads();                                                          \
        bf16x8 af[4], bfr[4];                                                     \
        _Pragma("unroll")                                                         \
        for (int i = 0; i < 4; ++i) {                                             \
            af[i]  = *(const bf16x8*)&As[(wm * 64 + i * 16 + l15) * 32 + fs];     \
            bfr[i] = *(const bf16x8*)&Bs[(wn * 64 + i * 16 + l15) * 32 + fs];     \
        }                                                                         \
        _Pragma("unroll")                                                         \
        for (int i = 0; i < 4; ++i)                                               \
            _Pragma("unroll")                                                     \
            for (int j = 0; j < 4; ++j)                                           \
                acc[i][j] = __builtin_amdgcn_mfma_f32_16x16x32_bf16(              \
                    af[i], bfr[j], acc[i][j], 0, 0, 0);                           \
    }

// qkv = x @ w_qkv^T; Q,K bf16 [h][t][d] (pre-norm), V bf16 transposed [hkv][d][t]
__global__ __launch_bounds__(256)
void gemm_qkv_mfma(const unsigned short* __restrict__ A,
                   const unsigned short* __restrict__ B,
                   unsigned short* __restrict__ qbf,
                   unsigned short* __restrict__ kbf,
                   unsigned short* __restrict__ vbf)
{
    GEMM_MAINLOOP(A, B, 1024)
    #pragma unroll
    for (int i = 0; i < 4; ++i) {
        #pragma unroll
        for (int j = 0; j < 4; ++j) {
            const int n = n0 + wn * 64 + j * 16 + l15;
            #pragma unroll
            for (int r = 0; r < 4; ++r) {
                const int t = m0 + wm * 64 + i * 16 + quad * 4 + r;
                const unsigned short v = f2bf(acc[i][j][r]);
                if (n < D) {
                    qbf[((size_t)(n >> 6) * Tq + t) * HD + (n & 63)] = v;
                } else if (n < D + 256) {
                    kbf[((size_t)((n - D) >> 6) * Tq + t) * HD + (n & 63)] = v;
                } else {
                    vbf[((size_t)((n - D - 256) >> 6) * HD + (n & 63)) * Tq + t] = v;
                }
            }
        }
    }
}

// out = y @ w_proj^T  (f32 output)
__global__ __launch_bounds__(256)
void gemm_proj_mfma(const unsigned short* __restrict__ A,
                    const unsigned short* __restrict__ B,
                    float* __restrict__ C)
{
    GEMM_MAINLOOP(A, B, 1024)
    #pragma unroll
    for (int i = 0; i < 4; ++i) {
        #pragma unroll
        for (int j = 0; j < 4; ++j) {
            const int n = n0 + wn * 64 + j * 16 + l15;
            #pragma unroll
            for (int r = 0; r < 4; ++r) {
                const int t = m0 + wm * 64 + i * 16 + quad * 4 + r;
                C[(size_t)t * D + n] = acc[i][j][r];
            }
        }
    }
}

// ---------------------------------------------------------------------------
// Per-row (t, head) RMS norm + rotary + gain, bf16 in/out in place.
// ---------------------------------------------------------------------------
__global__ __launch_bounds__(256)
void norm_rope(unsigned short* __restrict__ qbf, unsigned short* __restrict__ kbf,
               const float* __restrict__ gain)
{
    const int tid  = threadIdx.x;
    const int lane = tid & 63;
    const long row = (long)blockIdx.x * 4 + (tid >> 6);
    const long QROWS = (long)H * Tq;

    unsigned short* base;
    int t;
    float g;
    if (row < QROWS) {
        base = qbf + row * HD;
        t = (int)(row & (Tq - 1));
        g = gain[row >> 12];
    } else {
        const long r2 = row - QROWS;
        base = kbf + r2 * HD;
        t = (int)(r2 & (Tq - 1));
        g = 1.0f;
    }

    float v = bf2f(base[lane]);
    float ss = v * v;
    #pragma unroll
    for (int m = 1; m < 64; m <<= 1) ss += __shfl_xor(ss, m);
    const float rms = rsqrtf(ss * (1.0f / 64.0f) + 1.1920929e-07f);
    const float vn = v * rms;
    const float p = __shfl_xor(vn, 32);

    const int i = lane & 31;
    const float invf = __expf((float)i * -0.28782313662425572f);
    const float ang = (float)t * invf;
    float s, c;
    sincosf(ang, &s, &c);
    const float res = vn * c + ((lane < 32) ? p * s : -(p * s));
    base[lane] = f2bf(res * g);
}

// ---------------------------------------------------------------------------
// Flash attention, bf16 MFMA. Core K-loop identical to rounds 5-8 (verified).
//
// EXACT-THIRDS: pair (qt_L=64+j, qt_S=63-j) has total work T = n_L+n_S = 65
// key-tiles for EVERY j. Grid (256,3): slot s covers concatenated units
// [u0,u1) with boundaries {0,21,43,65} -> pieces {21,22,22}: every CU's 3
// co-resident blocks (same bx) run equal-duration pieces; 12 waves stay
// resident to the end. A piece may straddle the L/S boundary -> up to 2
// segments (qt, kb, ke). ALL output is associative bf16 o-partials + f32 l
// into slot buffers (static-max softmax: no rescale); merge_all sums the
// statically-known contributing slots per row and normalizes.
// ---------------------------------------------------------------------------
__global__ __launch_bounds__(256, 3)
void attn_mfma(const unsigned short* __restrict__ qbf,
               const unsigned short* __restrict__ kbf,
               const unsigned short* __restrict__ vbf,
               unsigned short* __restrict__ o0, unsigned short* __restrict__ o1,
               unsigned short* __restrict__ o2,
               float* __restrict__ lp0, float* __restrict__ lp1,
               float* __restrict__ lp2)
{
    __shared__ __align__(16) unsigned short Ks[64 * 72];   // [key][d]
    __shared__ __align__(16) unsigned short Vs[64 * 72];   // [d][key]
    __shared__ __align__(16) unsigned short Ps[4][32 * 72]; // per-wave [q][key]

    const int s    = blockIdx.y;              // slot 0..2
    const int hkv  = blockIdx.x >> 6;
    const int j    = blockIdx.x & 63;
    const int qt_L = 64 + j;
    const int qt_S = 63 - j;
    const int n_L  = (qt_L >> 1) + 1;
    const int u0   = (s == 0) ? 0 : (s == 1) ? 21 : 43;
    const int u1   = (s == 0) ? 21 : (s == 1) ? 43 : 65;

    // up to 2 segments (qt, kb, ke)
    int sq[2], sb[2], se[2], nseg = 0;
    if (u0 < n_L) { sq[nseg] = qt_L; sb[nseg] = u0;
                    se[nseg] = (u1 < n_L) ? u1 : n_L; ++nseg; }
    if (u1 > n_L) { sq[nseg] = qt_S; sb[nseg] = (u0 > n_L ? u0 : n_L) - n_L;
                    se[nseg] = u1 - n_L; ++nseg; }

    const int tid  = threadIdx.x;
    const int lane = tid & 63;
    const int w    = tid >> 6;
    const int h    = hkv * 4 + w;             // this wave's query head
    const int l15  = lane & 15;
    const int quad = lane >> 4;

    const unsigned short* kB = kbf + (size_t)hkv * Tq * HD;
    const unsigned short* vB = vbf + (size_t)hkv * HD * Tq;

    unsigned short* oX = (s == 0) ? o0 : (s == 1) ? o1 : o2;
    float*          lX = (s == 0) ? lp0 : (s == 1) ? lp1 : lp2;

    // staging geometry: 256 threads stage the 64x64 K tile and V tile
    const int srow = tid >> 2;           // 0..63
    const int sc   = (tid & 3) * 16;     // column offset in shorts

    for (int g = 0; g < nseg; ++g) {
        const int qt  = sq[g];
        const int kb  = sb[g];
        const int ke  = se[g];
        const int nkt = (qt >> 1) + 1;
        const int q0  = qt * 32;

        // Q fragments as MFMA B-operand: B[k=d][n=q]: lane n=l15, k=quad*8+jj
        bf16x8 qf[2][2];
        #pragma unroll
        for (int nt = 0; nt < 2; ++nt)
            #pragma unroll
            for (int ks = 0; ks < 2; ++ks)
                qf[nt][ks] = *(const bf16x8*)(qbf +
                    ((size_t)h * Tq + q0 + nt * 16 + l15) * HD + ks * 32 + quad * 8);

        f32x4 o[2][4];     // [q-subtile][d-subtile]
        float lp[2] = {0.f, 0.f};
        #pragma unroll
        for (int i = 0; i < 2; ++i)
            #pragma unroll
            for (int jj = 0; jj < 4; ++jj) o[i][jj] = (f32x4){0.f, 0.f, 0.f, 0.f};

        // preload tile kb into registers
        float4 k0r = *(const float4*)(kB + (size_t)(kb * 64 + srow) * HD + sc);
        float4 k1r = *(const float4*)(kB + (size_t)(kb * 64 + srow) * HD + sc + 8);
        float4 v0r = *(const float4*)(vB + (size_t)srow * Tq + kb * 64 + sc);
        float4 v1r = *(const float4*)(vB + (size_t)srow * Tq + kb * 64 + sc + 8);

        for (int kt = kb; kt < ke; ++kt) {
            // stage current tile regs -> LDS (prev iter's reads done)
            *(float4*)&Ks[srow * 72 + sc]     = k0r;
            *(float4*)&Ks[srow * 72 + sc + 8] = k1r;
            *(float4*)&Vs[srow * 72 + sc]     = v0r;
            *(float4*)&Vs[srow * 72 + sc + 8] = v1r;

            // issue next tile's global loads; vmcnt waited a full phase later
            if (kt + 1 < ke) {
                const int kbt = (kt + 1) * 64;
                k0r = *(const float4*)(kB + (size_t)(kbt + srow) * HD + sc);
                k1r = *(const float4*)(kB + (size_t)(kbt + srow) * HD + sc + 8);
                v0r = *(const float4*)(vB + (size_t)srow * Tq + kbt + sc);
                v1r = *(const float4*)(vB + (size_t)srow * Tq + kbt + sc + 8);
            }
            __syncthreads();   // tile kt visible to all waves

            // S^T = K Q^T : D[m=key][n=q]; kf (A-frag) reused across q-tiles
            f32x4 sacc[4][2];
            #pragma unroll
            for (int mt = 0; mt < 4; ++mt)
                #pragma unroll
                for (int nt = 0; nt < 2; ++nt) sacc[mt][nt] = (f32x4){0.f, 0.f, 0.f, 0.f};
            #pragma unroll
            for (int ks = 0; ks < 2; ++ks) {
                #pragma unroll
                for (int mt = 0; mt < 4; ++mt) {
                    bf16x8 kf = *(const bf16x8*)&Ks[(mt * 16 + l15) * 72 + quad * 8 + ks * 32];
                    #pragma unroll
                    for (int nt = 0; nt < 2; ++nt)
                        sacc[mt][nt] = __builtin_amdgcn_mfma_f32_16x16x32_bf16(
                            kf, qf[nt][ks], sacc[mt][nt], 0, 0, 0);
                }
            }

            // softmax: lane holds keys (quad*4+r) x q (l15); 4 keys -> b64
            if (kt < nkt - 1) {   // fully unmasked tile
                #pragma unroll
                for (int mt = 0; mt < 4; ++mt)
                    #pragma unroll
                    for (int nt = 0; nt < 2; ++nt) {
                        ushort4 pk;
                        float p0 = __expf(fmaf(sacc[mt][nt][0], 0.125f, -22.0f));
                        float p1 = __expf(fmaf(sacc[mt][nt][1], 0.125f, -22.0f));
                        float p2 = __expf(fmaf(sacc[mt][nt][2], 0.125f, -22.0f));
                        float p3 = __expf(fmaf(sacc[mt][nt][3], 0.125f, -22.0f));
                        lp[nt] += p0 + p1 + p2 + p3;
                        pk.x = rnbf(p0); pk.y = rnbf(p1); pk.z = rnbf(p2); pk.w = rnbf(p3);
                        *(ushort4*)&Ps[w][(nt * 16 + l15) * 72 + mt * 16 + quad * 4] = pk;
                    }
            } else {              // diagonal tile: mask key > q
                #pragma unroll
                for (int mt = 0; mt < 4; ++mt)
                    #pragma unroll
                    for (int nt = 0; nt < 2; ++nt) {
                        const int kglo = kt * 64 + mt * 16 + quad * 4;
                        const int qglo = q0 + nt * 16 + l15;
                        ushort4 pk;
                        float ps = 0.f;
                        float pv[4];
                        #pragma unroll
                        for (int r = 0; r < 4; ++r) {
                            float p = __expf(fmaf(sacc[mt][nt][r], 0.125f, -22.0f));
                            if (kglo + r > qglo) p = 0.f;
                            pv[r] = p; ps += p;
                        }
                        lp[nt] += ps;
                        pk.x = rnbf(pv[0]); pk.y = rnbf(pv[1]);
                        pk.z = rnbf(pv[2]); pk.w = rnbf(pv[3]);
                        *(ushort4*)&Ps[w][(nt * 16 + l15) * 72 + mt * 16 + quad * 4] = pk;
                    }
            }

            // O += P V : A-frag from per-wave Ps (b128), B-frag from Vs rows
            #pragma unroll
            for (int ks = 0; ks < 2; ++ks) {
                bf16x8 pf0 = *(const bf16x8*)&Ps[w][(l15) * 72 + quad * 8 + ks * 32];
                bf16x8 pf1 = *(const bf16x8*)&Ps[w][(16 + l15) * 72 + quad * 8 + ks * 32];
                #pragma unroll
                for (int nt = 0; nt < 4; ++nt) {
                    bf16x8 vf = *(const bf16x8*)&Vs[(nt * 16 + l15) * 72 + quad * 8 + ks * 32];
                    o[0][nt] = __builtin_amdgcn_mfma_f32_16x16x32_bf16(pf0, vf, o[0][nt], 0, 0, 0);
                    o[1][nt] = __builtin_amdgcn_mfma_f32_16x16x32_bf16(pf1, vf, o[1][nt], 0, 0, 0);
                }
            }
            __syncthreads();   // all waves done reading Ks/Vs before next stage
        }

        // segment epilogue: raw bf16 o-partials + f32 l into slot s
        float l0 = lp[0], l1 = lp[1];
        l0 += __shfl_xor(l0, 16); l0 += __shfl_xor(l0, 32);
        l1 += __shfl_xor(l1, 16); l1 += __shfl_xor(l1, 32);
        if (quad == 0) {
            lX[h * Tq + q0 + l15]      = l0;
            lX[h * Tq + q0 + 16 + l15] = l1;
        }
        #pragma unroll
        for (int r = 0; r < 4; ++r) {
            const int qa = q0 + quad * 4 + r;
            #pragma unroll
            for (int nt = 0; nt < 4; ++nt) {
                oX[((size_t)h * Tq + qa) * 64 + nt * 16 + l15]      = f2bf(o[0][nt][r]);
                oX[((size_t)h * Tq + qa + 16) * 64 + nt * 16 + l15] = f2bf(o[1][nt][r]);
            }
        }
    }
}

// ---------------------------------------------------------------------------
// merge the slot partials for every row; slots contributing to a row are
// statically known from (qt, j): L-rows (qt>=64): slots {0,1} + {2 iff 43<n_L};
// S-rows (qt<64): slot {2} + {1 iff 43>n_L}. Normalize and write bf16 y.
// ---------------------------------------------------------------------------
__global__ __launch_bounds__(256)
void merge_all(const unsigned short* __restrict__ o0,
               const unsigned short* __restrict__ o1,
               const unsigned short* __restrict__ o2,
               const float* __restrict__ lp0, const float* __restrict__ lp1,
               const float* __restrict__ lp2,
               unsigned short* __restrict__ ybf)
{
    const int i  = (blockIdx.x * 256 + threadIdx.x) * 4;   // over 16*4096*64
    const int d0 = i & 63;
    const int q  = (i >> 6) & 4095;
    const int h  = i >> 18;
    const int qt = q >> 5;
    const bool isL = (qt >= 64);
    const int j   = isL ? (qt - 64) : (63 - qt);
    const int n_L = ((64 + j) >> 1) + 1;

    const bool c0 = isL;
    const bool c1 = isL || (43 > n_L);
    const bool c2 = (!isL) || (43 < n_L);

    float acc[4] = {0.f, 0.f, 0.f, 0.f};
    float lsum = 0.f;
    const size_t ob = (size_t)(h * Tq + q) * 64 + d0;
    const int    lb = h * Tq + q;
    if (c0) {
        ushort4 a = *(const ushort4*)(o0 + ob);
        acc[0] += bf2f(a.x); acc[1] += bf2f(a.y);
        acc[2] += bf2f(a.z); acc[3] += bf2f(a.w);
        lsum += lp0[lb];
    }
    if (c1) {
        ushort4 a = *(const ushort4*)(o1 + ob);
        acc[0] += bf2f(a.x); acc[1] += bf2f(a.y);
        acc[2] += bf2f(a.z); acc[3] += bf2f(a.w);
        lsum += lp1[lb];
    }
    if (c2) {
        ushort4 a = *(const ushort4*)(o2 + ob);
        acc[0] += bf2f(a.x); acc[1] += bf2f(a.y);
        acc[2] += bf2f(a.z); acc[3] += bf2f(a.w);
        lsum += lp2[lb];
    }
    const float linv = 1.0f / lsum;
    ushort4 y;
    y.x = f2bf(acc[0] * linv);
    y.y = f2bf(acc[1] * linv);
    y.z = f2bf(acc[2] * linv);
    y.w = f2bf(acc[3] * linv);
    *(ushort4*)(ybf + (size_t)q * D + h * 64 + d0) = y;
}

// ---------------------------------------------------------------------------
extern "C" void kernel_launch(void* const* d_in, const int* in_sizes, int n_in,
                              void* d_out, int out_size, void* d_ws, size_t ws_size,
                              hipStream_t stream)
{
    const float* x      = (const float*)d_in[0];   // [1, 4096, 1024]
    const float* w_qkv  = (const float*)d_in[1];   // [1536, 1024]
    const float* w_proj = (const float*)d_in[2];   // [1024, 1024]
    const float* q_gain = (const float*)d_in[3];   // [16]
    float* out = (float*)d_out;                    // [4096, 1024]

    // workspace layout (bf16 elements unless noted)
    unsigned short* qbf = (unsigned short*)d_ws;              // 4M elts
    unsigned short* kbf = qbf + (size_t)H * Tq * HD;          // 1M
    unsigned short* vbf = kbf + (size_t)HKV * Tq * HD;        // 1M
    unsigned short* ybf = vbf + (size_t)HKV * Tq * HD;        // 4M
    unsigned short* xbf = ybf + (size_t)Tq * D;               // 4M
    unsigned short* wqkvbf  = xbf + (size_t)Tq * D;           // 1.5M
    unsigned short* wprojbf = wqkvbf + (size_t)NQKV * D;      // 1M

    // attention slot buffers: o0 aliases xbf (dead after gemm_qkv), l slots
    // alias wqkvbf (dead after gemm_qkv); o1/o2 fresh.
    unsigned short* o0 = xbf;                                  // 8 MB (alias)
    float* lp0 = (float*)wqkvbf;                               // 256 KB (alias)
    float* lp1 = lp0 + (size_t)H * Tq;
    float* lp2 = lp1 + (size_t)H * Tq;                         // total 768 KB < 3 MB
    unsigned short* o1 = wprojbf + (size_t)D * D;              // fresh 8 MB
    unsigned short* o2 = o1 + (size_t)H * Tq * HD;             // fresh 8 MB

    const int NTOT = Tq * D + NQKV * D + D * D;
    to_bf16_all<<<dim3(NTOT / 1024), 256, 0, stream>>>(x, w_qkv, w_proj,
                                                       xbf, wqkvbf, wprojbf);

    gemm_qkv_mfma<<<dim3(Tq / 128, NQKV / 128), 256, 0, stream>>>(xbf, wqkvbf, qbf, kbf, vbf);
    norm_rope<<<dim3((H + HKV) * Tq / 4), 256, 0, stream>>>(qbf, kbf, q_gain);
    attn_mfma<<<dim3(256, 3), 256, 0, stream>>>(qbf, kbf, vbf, o0, o1, o2,
                                                lp0, lp1, lp2);
    merge_all<<<dim3(H * Tq * HD / 1024), 256, 0, stream>>>(o0, o1, o2,
                                                            lp0, lp1, lp2, ybf);
    gemm_proj_mfma<<<dim3(Tq / 128, D / 128), 256, 0, stream>>>(ybf, wprojbf, out);
}

// Round 10
// 194.497 us; speedup vs baseline: 1.0515x; 1.0515x over previous
//
#include <hip/hip_runtime.h>
#include <hip/hip_bf16.h>
#include <math.h>

// Problem constants
constexpr int Tq  = 4096;   // sequence length
constexpr int D   = 1024;   // model dim
constexpr int H   = 16;     // query heads
constexpr int HKV = 4;      // kv heads
constexpr int HD  = 64;     // head dim
constexpr int NQKV = D + 2 * HKV * HD;   // 1536

typedef __attribute__((ext_vector_type(8))) short bf16x8;
typedef __attribute__((ext_vector_type(4))) float f32x4;

static __device__ inline unsigned short f2bf(float f) {
    __hip_bfloat16 h = __float2bfloat16(f);
    return *reinterpret_cast<unsigned short*>(&h);
}
static __device__ inline unsigned short rnbf(float f) {   // RN for positive finite
    unsigned int u = __float_as_uint(f);
    return (unsigned short)((u + 0x8000u) >> 16);
}
static __device__ inline float bf2f(unsigned short u) {
    unsigned int x = ((unsigned int)u) << 16;
    return __uint_as_float(x);
}

#define GLOBAL_LOAD_LDS16(g, l)                                                   \
    __builtin_amdgcn_global_load_lds(                                             \
        (const __attribute__((address_space(1))) void*)(g),                       \
        (__attribute__((address_space(3))) void*)(l), 16, 0, 0)

// ---------------------------------------------------------------------------
// fused f32 -> bf16 convert for x, w_qkv, w_proj (one launch)
// ---------------------------------------------------------------------------
__global__ __launch_bounds__(256)
void to_bf16_all(const float* __restrict__ x, const float* __restrict__ wq,
                 const float* __restrict__ wp,
                 unsigned short* __restrict__ xb, unsigned short* __restrict__ wqb,
                 unsigned short* __restrict__ wpb)
{
    const int N1 = Tq * D, N2 = NQKV * D;
    int i = (blockIdx.x * 256 + threadIdx.x) * 4;
    const float* s; unsigned short* d;
    if (i < N1)            { s = x + i;             d = xb + i; }
    else if (i < N1 + N2)  { s = wq + (i - N1);     d = wqb + (i - N1); }
    else                   { s = wp + (i - N1 - N2); d = wpb + (i - N1 - N2); }
    float4 v = *(const float4*)s;
    ushort4 o;
    o.x = f2bf(v.x); o.y = f2bf(v.y); o.z = f2bf(v.z); o.w = f2bf(v.w);
    *(ushort4*)d = o;
}

// ---------------------------------------------------------------------------
// bf16 MFMA GEMM mainloop: C[M,N] = A[M,K] @ B[N,K]^T
// 128(M) x 64(N) tile, BK=32, 4 waves in 2x2 (each 64x32): raises grid to
// 2-3 blocks/CU for these small-N shapes (m102: 1 block/CU starves the
// K-loop of cross-block overlap). Swizzle identities verified for 64-row B.
// ---------------------------------------------------------------------------
#define GEMM_MAINLOOP(Aptr, Bptr, Kdim)                                           \
    __shared__ __align__(16) unsigned short As[128 * 32];                         \
    __shared__ __align__(16) unsigned short Bs[64 * 32];                          \
    const int tid  = threadIdx.x;                                                 \
    const int lane = tid & 63;                                                    \
    const int w    = tid >> 6;                                                    \
    const int l15  = lane & 15, quad = lane >> 4;                                 \
    const int wm   = w >> 1, wn = w & 1;                                          \
    const int m0   = blockIdx.x * 128, n0 = blockIdx.y * 64;                      \
    const int srow   = lane >> 2;                                                 \
    const int schunk = (lane & 3) ^ ((lane >> 3) & 3);                            \
    const int fs     = (quad ^ ((l15 >> 1) & 3)) * 8;                             \
    f32x4 acc[4][2];                                                              \
    _Pragma("unroll")                                                             \
    for (int i = 0; i < 4; ++i)                                                   \
        _Pragma("unroll")                                                         \
        for (int j = 0; j < 2; ++j) acc[i][j] = (f32x4){0.f, 0.f, 0.f, 0.f};      \
    for (int k0 = 0; k0 < (Kdim); k0 += 32) {                                     \
        __syncthreads();                                                          \
        _Pragma("unroll")                                                         \
        for (int it = 0; it < 2; ++it) {                                          \
            const int r = w * 32 + it * 16 + srow;                                \
            GLOBAL_LOAD_LDS16((Aptr) + (size_t)(m0 + r) * (Kdim) + k0 + schunk * 8,\
                              &As[(w * 32 + it * 16) * 32]);                      \
        }                                                                         \
        {                                                                         \
            const int r = w * 16 + srow;                                          \
            GLOBAL_LOAD_LDS16((Bptr) + (size_t)(n0 + r) * (Kdim) + k0 + schunk * 8,\
                              &Bs[(w * 16) * 32]);                                \
        }                                                                         \
        __syncthreads();                                                          \
        bf16x8 af[4], bfr[2];                                                     \
        _Pragma("unroll")                                                         \
        for (int i = 0; i < 4; ++i)                                               \
            af[i]  = *(const bf16x8*)&As[(wm * 64 + i * 16 + l15) * 32 + fs];     \
        _Pragma("unroll")                                                         \
        for (int j = 0; j < 2; ++j)                                               \
            bfr[j] = *(const bf16x8*)&Bs[(wn * 32 + j * 16 + l15) * 32 + fs];     \
        _Pragma("unroll")                                                         \
        for (int i = 0; i < 4; ++i)                                               \
            _Pragma("unroll")                                                     \
            for (int j = 0; j < 2; ++j)                                           \
                acc[i][j] = __builtin_amdgcn_mfma_f32_16x16x32_bf16(              \
                    af[i], bfr[j], acc[i][j], 0, 0, 0);                           \
    }

// qkv = x @ w_qkv^T; Q,K bf16 [h][t][d] (pre-norm), V bf16 transposed [hkv][d][t]
__global__ __launch_bounds__(256)
void gemm_qkv_mfma(const unsigned short* __restrict__ A,
                   const unsigned short* __restrict__ B,
                   unsigned short* __restrict__ qbf,
                   unsigned short* __restrict__ kbf,
                   unsigned short* __restrict__ vbf)
{
    GEMM_MAINLOOP(A, B, 1024)
    #pragma unroll
    for (int i = 0; i < 4; ++i) {
        #pragma unroll
        for (int j = 0; j < 2; ++j) {
            const int n = n0 + wn * 32 + j * 16 + l15;
            #pragma unroll
            for (int r = 0; r < 4; ++r) {
                const int t = m0 + wm * 64 + i * 16 + quad * 4 + r;
                const unsigned short v = f2bf(acc[i][j][r]);
                if (n < D) {
                    qbf[((size_t)(n >> 6) * Tq + t) * HD + (n & 63)] = v;
                } else if (n < D + 256) {
                    kbf[((size_t)((n - D) >> 6) * Tq + t) * HD + (n & 63)] = v;
                } else {
                    vbf[((size_t)((n - D - 256) >> 6) * HD + (n & 63)) * Tq + t] = v;
                }
            }
        }
    }
}

// out = y @ w_proj^T  (f32 output)
__global__ __launch_bounds__(256)
void gemm_proj_mfma(const unsigned short* __restrict__ A,
                    const unsigned short* __restrict__ B,
                    float* __restrict__ C)
{
    GEMM_MAINLOOP(A, B, 1024)
    #pragma unroll
    for (int i = 0; i < 4; ++i) {
        #pragma unroll
        for (int j = 0; j < 2; ++j) {
            const int n = n0 + wn * 32 + j * 16 + l15;
            #pragma unroll
            for (int r = 0; r < 4; ++r) {
                const int t = m0 + wm * 64 + i * 16 + quad * 4 + r;
                C[(size_t)t * D + n] = acc[i][j][r];
            }
        }
    }
}

// ---------------------------------------------------------------------------
// Per-row (t, head) RMS norm + rotary + gain, bf16 in/out in place.
// ---------------------------------------------------------------------------
__global__ __launch_bounds__(256)
void norm_rope(unsigned short* __restrict__ qbf, unsigned short* __restrict__ kbf,
               const float* __restrict__ gain)
{
    const int tid  = threadIdx.x;
    const int lane = tid & 63;
    const long row = (long)blockIdx.x * 4 + (tid >> 6);
    const long QROWS = (long)H * Tq;

    unsigned short* base;
    int t;
    float g;
    if (row < QROWS) {
        base = qbf + row * HD;
        t = (int)(row & (Tq - 1));
        g = gain[row >> 12];
    } else {
        const long r2 = row - QROWS;
        base = kbf + r2 * HD;
        t = (int)(r2 & (Tq - 1));
        g = 1.0f;
    }

    float v = bf2f(base[lane]);
    float ss = v * v;
    #pragma unroll
    for (int m = 1; m < 64; m <<= 1) ss += __shfl_xor(ss, m);
    const float rms = rsqrtf(ss * (1.0f / 64.0f) + 1.1920929e-07f);
    const float vn = v * rms;
    const float p = __shfl_xor(vn, 32);

    const int i = lane & 31;
    const float invf = __expf((float)i * -0.28782313662425572f);
    const float ang = (float)t * invf;
    float s, c;
    sincosf(ang, &s, &c);
    const float res = vn * c + ((lane < 32) ? p * s : -(p * s));
    base[lane] = f2bf(res * g);
}

// ---------------------------------------------------------------------------
// Flash attention, bf16 MFMA. Core K-loop identical to rounds 5-9 (verified).
// EXACT-THIRDS decomposition (round 9): grid (256,3), slot pieces {21,22,22}
// of each pair's 65 key-tile total; partials merged by merge_all.
// ---------------------------------------------------------------------------
__global__ __launch_bounds__(256, 3)
void attn_mfma(const unsigned short* __restrict__ qbf,
               const unsigned short* __restrict__ kbf,
               const unsigned short* __restrict__ vbf,
               unsigned short* __restrict__ o0, unsigned short* __restrict__ o1,
               unsigned short* __restrict__ o2,
               float* __restrict__ lp0, float* __restrict__ lp1,
               float* __restrict__ lp2)
{
    __shared__ __align__(16) unsigned short Ks[64 * 72];   // [key][d]
    __shared__ __align__(16) unsigned short Vs[64 * 72];   // [d][key]
    __shared__ __align__(16) unsigned short Ps[4][32 * 72]; // per-wave [q][key]

    const int s    = blockIdx.y;              // slot 0..2
    const int hkv  = blockIdx.x >> 6;
    const int j    = blockIdx.x & 63;
    const int qt_L = 64 + j;
    const int qt_S = 63 - j;
    const int n_L  = (qt_L >> 1) + 1;
    const int u0   = (s == 0) ? 0 : (s == 1) ? 21 : 43;
    const int u1   = (s == 0) ? 21 : (s == 1) ? 43 : 65;

    // up to 2 segments (qt, kb, ke)
    int sq[2], sb[2], se[2], nseg = 0;
    if (u0 < n_L) { sq[nseg] = qt_L; sb[nseg] = u0;
                    se[nseg] = (u1 < n_L) ? u1 : n_L; ++nseg; }
    if (u1 > n_L) { sq[nseg] = qt_S; sb[nseg] = (u0 > n_L ? u0 : n_L) - n_L;
                    se[nseg] = u1 - n_L; ++nseg; }

    const int tid  = threadIdx.x;
    const int lane = tid & 63;
    const int w    = tid >> 6;
    const int h    = hkv * 4 + w;             // this wave's query head
    const int l15  = lane & 15;
    const int quad = lane >> 4;

    const unsigned short* kB = kbf + (size_t)hkv * Tq * HD;
    const unsigned short* vB = vbf + (size_t)hkv * HD * Tq;

    unsigned short* oX = (s == 0) ? o0 : (s == 1) ? o1 : o2;
    float*          lX = (s == 0) ? lp0 : (s == 1) ? lp1 : lp2;

    // staging geometry: 256 threads stage the 64x64 K tile and V tile
    const int srow = tid >> 2;           // 0..63
    const int sc   = (tid & 3) * 16;     // column offset in shorts

    for (int g = 0; g < nseg; ++g) {
        const int qt  = sq[g];
        const int kb  = sb[g];
        const int ke  = se[g];
        const int nkt = (qt >> 1) + 1;
        const int q0  = qt * 32;

        // Q fragments as MFMA B-operand: B[k=d][n=q]: lane n=l15, k=quad*8+jj
        bf16x8 qf[2][2];
        #pragma unroll
        for (int nt = 0; nt < 2; ++nt)
            #pragma unroll
            for (int ks = 0; ks < 2; ++ks)
                qf[nt][ks] = *(const bf16x8*)(qbf +
                    ((size_t)h * Tq + q0 + nt * 16 + l15) * HD + ks * 32 + quad * 8);

        f32x4 o[2][4];     // [q-subtile][d-subtile]
        float lp[2] = {0.f, 0.f};
        #pragma unroll
        for (int i = 0; i < 2; ++i)
            #pragma unroll
            for (int jj = 0; jj < 4; ++jj) o[i][jj] = (f32x4){0.f, 0.f, 0.f, 0.f};

        // preload tile kb into registers
        float4 k0r = *(const float4*)(kB + (size_t)(kb * 64 + srow) * HD + sc);
        float4 k1r = *(const float4*)(kB + (size_t)(kb * 64 + srow) * HD + sc + 8);
        float4 v0r = *(const float4*)(vB + (size_t)srow * Tq + kb * 64 + sc);
        float4 v1r = *(const float4*)(vB + (size_t)srow * Tq + kb * 64 + sc + 8);

        for (int kt = kb; kt < ke; ++kt) {
            // stage current tile regs -> LDS (prev iter's reads done)
            *(float4*)&Ks[srow * 72 + sc]     = k0r;
            *(float4*)&Ks[srow * 72 + sc + 8] = k1r;
            *(float4*)&Vs[srow * 72 + sc]     = v0r;
            *(float4*)&Vs[srow * 72 + sc + 8] = v1r;

            // issue next tile's global loads; vmcnt waited a full phase later
            if (kt + 1 < ke) {
                const int kbt = (kt + 1) * 64;
                k0r = *(const float4*)(kB + (size_t)(kbt + srow) * HD + sc);
                k1r = *(const float4*)(kB + (size_t)(kbt + srow) * HD + sc + 8);
                v0r = *(const float4*)(vB + (size_t)srow * Tq + kbt + sc);
                v1r = *(const float4*)(vB + (size_t)srow * Tq + kbt + sc + 8);
            }
            __syncthreads();   // tile kt visible to all waves

            // S^T = K Q^T : D[m=key][n=q]; kf (A-frag) reused across q-tiles
            f32x4 sacc[4][2];
            #pragma unroll
            for (int mt = 0; mt < 4; ++mt)
                #pragma unroll
                for (int nt = 0; nt < 2; ++nt) sacc[mt][nt] = (f32x4){0.f, 0.f, 0.f, 0.f};
            #pragma unroll
            for (int ks = 0; ks < 2; ++ks) {
                #pragma unroll
                for (int mt = 0; mt < 4; ++mt) {
                    bf16x8 kf = *(const bf16x8*)&Ks[(mt * 16 + l15) * 72 + quad * 8 + ks * 32];
                    #pragma unroll
                    for (int nt = 0; nt < 2; ++nt)
                        sacc[mt][nt] = __builtin_amdgcn_mfma_f32_16x16x32_bf16(
                            kf, qf[nt][ks], sacc[mt][nt], 0, 0, 0);
                }
            }

            // softmax: lane holds keys (quad*4+r) x q (l15); 4 keys -> b64
            if (kt < nkt - 1) {   // fully unmasked tile
                #pragma unroll
                for (int mt = 0; mt < 4; ++mt)
                    #pragma unroll
                    for (int nt = 0; nt < 2; ++nt) {
                        ushort4 pk;
                        float p0 = __expf(fmaf(sacc[mt][nt][0], 0.125f, -22.0f));
                        float p1 = __expf(fmaf(sacc[mt][nt][1], 0.125f, -22.0f));
                        float p2 = __expf(fmaf(sacc[mt][nt][2], 0.125f, -22.0f));
                        float p3 = __expf(fmaf(sacc[mt][nt][3], 0.125f, -22.0f));
                        lp[nt] += p0 + p1 + p2 + p3;
                        pk.x = rnbf(p0); pk.y = rnbf(p1); pk.z = rnbf(p2); pk.w = rnbf(p3);
                        *(ushort4*)&Ps[w][(nt * 16 + l15) * 72 + mt * 16 + quad * 4] = pk;
                    }
            } else {              // diagonal tile: mask key > q
                #pragma unroll
                for (int mt = 0; mt < 4; ++mt)
                    #pragma unroll
                    for (int nt = 0; nt < 2; ++nt) {
                        const int kglo = kt * 64 + mt * 16 + quad * 4;
                        const int qglo = q0 + nt * 16 + l15;
                        ushort4 pk;
                        float ps = 0.f;
                        float pv[4];
                        #pragma unroll
                        for (int r = 0; r < 4; ++r) {
                            float p = __expf(fmaf(sacc[mt][nt][r], 0.125f, -22.0f));
                            if (kglo + r > qglo) p = 0.f;
                            pv[r] = p; ps += p;
                        }
                        lp[nt] += ps;
                        pk.x = rnbf(pv[0]); pk.y = rnbf(pv[1]);
                        pk.z = rnbf(pv[2]); pk.w = rnbf(pv[3]);
                        *(ushort4*)&Ps[w][(nt * 16 + l15) * 72 + mt * 16 + quad * 4] = pk;
                    }
            }

            // O += P V : A-frag from per-wave Ps (b128), B-frag from Vs rows
            #pragma unroll
            for (int ks = 0; ks < 2; ++ks) {
                bf16x8 pf0 = *(const bf16x8*)&Ps[w][(l15) * 72 + quad * 8 + ks * 32];
                bf16x8 pf1 = *(const bf16x8*)&Ps[w][(16 + l15) * 72 + quad * 8 + ks * 32];
                #pragma unroll
                for (int nt = 0; nt < 4; ++nt) {
                    bf16x8 vf = *(const bf16x8*)&Vs[(nt * 16 + l15) * 72 + quad * 8 + ks * 32];
                    o[0][nt] = __builtin_amdgcn_mfma_f32_16x16x32_bf16(pf0, vf, o[0][nt], 0, 0, 0);
                    o[1][nt] = __builtin_amdgcn_mfma_f32_16x16x32_bf16(pf1, vf, o[1][nt], 0, 0, 0);
                }
            }
            __syncthreads();   // all waves done reading Ks/Vs before next stage
        }

        // segment epilogue: raw bf16 o-partials + f32 l into slot s
        float l0 = lp[0], l1 = lp[1];
        l0 += __shfl_xor(l0, 16); l0 += __shfl_xor(l0, 32);
        l1 += __shfl_xor(l1, 16); l1 += __shfl_xor(l1, 32);
        if (quad == 0) {
            lX[h * Tq + q0 + l15]      = l0;
            lX[h * Tq + q0 + 16 + l15] = l1;
        }
        #pragma unroll
        for (int r = 0; r < 4; ++r) {
            const int qa = q0 + quad * 4 + r;
            #pragma unroll
            for (int nt = 0; nt < 4; ++nt) {
                oX[((size_t)h * Tq + qa) * 64 + nt * 16 + l15]      = f2bf(o[0][nt][r]);
                oX[((size_t)h * Tq + qa + 16) * 64 + nt * 16 + l15] = f2bf(o[1][nt][r]);
            }
        }
    }
}

// ---------------------------------------------------------------------------
// merge the slot partials for every row; slots contributing to a row are
// statically known from (qt, j). Normalize and write bf16 y.
// ---------------------------------------------------------------------------
__global__ __launch_bounds__(256)
void merge_all(const unsigned short* __restrict__ o0,
               const unsigned short* __restrict__ o1,
               const unsigned short* __restrict__ o2,
               const float* __restrict__ lp0, const float* __restrict__ lp1,
               const float* __restrict__ lp2,
               unsigned short* __restrict__ ybf)
{
    const int i  = (blockIdx.x * 256 + threadIdx.x) * 4;   // over 16*4096*64
    const int d0 = i & 63;
    const int q  = (i >> 6) & 4095;
    const int h  = i >> 18;
    const int qt = q >> 5;
    const bool isL = (qt >= 64);
    const int j   = isL ? (qt - 64) : (63 - qt);
    const int n_L = ((64 + j) >> 1) + 1;

    const bool c0 = isL;
    const bool c1 = isL || (43 > n_L);
    const bool c2 = (!isL) || (43 < n_L);

    float acc[4] = {0.f, 0.f, 0.f, 0.f};
    float lsum = 0.f;
    const size_t ob = (size_t)(h * Tq + q) * 64 + d0;
    const int    lb = h * Tq + q;
    if (c0) {
        ushort4 a = *(const ushort4*)(o0 + ob);
        acc[0] += bf2f(a.x); acc[1] += bf2f(a.y);
        acc[2] += bf2f(a.z); acc[3] += bf2f(a.w);
        lsum += lp0[lb];
    }
    if (c1) {
        ushort4 a = *(const ushort4*)(o1 + ob);
        acc[0] += bf2f(a.x); acc[1] += bf2f(a.y);
        acc[2] += bf2f(a.z); acc[3] += bf2f(a.w);
        lsum += lp1[lb];
    }
    if (c2) {
        ushort4 a = *(const ushort4*)(o2 + ob);
        acc[0] += bf2f(a.x); acc[1] += bf2f(a.y);
        acc[2] += bf2f(a.z); acc[3] += bf2f(a.w);
        lsum += lp2[lb];
    }
    const float linv = 1.0f / lsum;
    ushort4 y;
    y.x = f2bf(acc[0] * linv);
    y.y = f2bf(acc[1] * linv);
    y.z = f2bf(acc[2] * linv);
    y.w = f2bf(acc[3] * linv);
    *(ushort4*)(ybf + (size_t)q * D + h * 64 + d0) = y;
}

// ---------------------------------------------------------------------------
extern "C" void kernel_launch(void* const* d_in, const int* in_sizes, int n_in,
                              void* d_out, int out_size, void* d_ws, size_t ws_size,
                              hipStream_t stream)
{
    const float* x      = (const float*)d_in[0];   // [1, 4096, 1024]
    const float* w_qkv  = (const float*)d_in[1];   // [1536, 1024]
    const float* w_proj = (const float*)d_in[2];   // [1024, 1024]
    const float* q_gain = (const float*)d_in[3];   // [16]
    float* out = (float*)d_out;                    // [4096, 1024]

    // workspace layout (bf16 elements unless noted)
    unsigned short* qbf = (unsigned short*)d_ws;              // 4M elts
    unsigned short* kbf = qbf + (size_t)H * Tq * HD;          // 1M
    unsigned short* vbf = kbf + (size_t)HKV * Tq * HD;        // 1M
    unsigned short* ybf = vbf + (size_t)HKV * Tq * HD;        // 4M
    unsigned short* xbf = ybf + (size_t)Tq * D;               // 4M
    unsigned short* wqkvbf  = xbf + (size_t)Tq * D;           // 1.5M
    unsigned short* wprojbf = wqkvbf + (size_t)NQKV * D;      // 1M

    // attention slot buffers: o0 aliases xbf (dead after gemm_qkv), l slots
    // alias wqkvbf (dead after gemm_qkv); o1/o2 fresh.
    unsigned short* o0 = xbf;                                  // 8 MB (alias)
    float* lp0 = (float*)wqkvbf;                               // 256 KB (alias)
    float* lp1 = lp0 + (size_t)H * Tq;
    float* lp2 = lp1 + (size_t)H * Tq;                         // total 768 KB < 3 MB
    unsigned short* o1 = wprojbf + (size_t)D * D;              // fresh 8 MB
    unsigned short* o2 = o1 + (size_t)H * Tq * HD;             // fresh 8 MB

    const int NTOT = Tq * D + NQKV * D + D * D;
    to_bf16_all<<<dim3(NTOT / 1024), 256, 0, stream>>>(x, w_qkv, w_proj,
                                                       xbf, wqkvbf, wprojbf);

    gemm_qkv_mfma<<<dim3(Tq / 128, NQKV / 64), 256, 0, stream>>>(xbf, wqkvbf, qbf, kbf, vbf);
    norm_rope<<<dim3((H + HKV) * Tq / 4), 256, 0, stream>>>(qbf, kbf, q_gain);
    attn_mfma<<<dim3(256, 3), 256, 0, stream>>>(qbf, kbf, vbf, o0, o1, o2,
                                                lp0, lp1, lp2);
    merge_all<<<dim3(H * Tq * HD / 1024), 256, 0, stream>>>(o0, o1, o2,
                                                            lp0, lp1, lp2, ybf);
    gemm_proj_mfma<<<dim3(Tq / 128, D / 64), 256, 0, stream>>>(ybf, wprojbf, out);
}